// Round 7
// baseline (308.762 us; speedup 1.0000x reference)
//
#include <hip/hip_runtime.h>
#include <hip/hip_bf16.h>
#include <math.h>

using bf16 = __hip_bfloat16;
typedef __bf16 bf16x8 __attribute__((ext_vector_type(8)));
typedef float  f32x4  __attribute__((ext_vector_type(4)));
typedef unsigned short ushort8 __attribute__((ext_vector_type(8)));

#define DEV __device__ __forceinline__

DEV void gld_lds16(const void* g, void* l) {
    __builtin_amdgcn_global_load_lds((const __attribute__((address_space(1))) void*)g,
                                     (__attribute__((address_space(3))) void*)l,
                                     16, 0, 0);
}

// ---------------- cast fp32 -> bf16 (flat) ----------------
__global__ __launch_bounds__(256) void cast_f32_bf16(const float* __restrict__ in,
                                                     bf16* __restrict__ out, int n4) {
    int i = blockIdx.x * blockDim.x + threadIdx.x;
    if (i >= n4) return;
    float4 f = ((const float4*)in)[i];
    __align__(8) bf16 o[4] = {__float2bfloat16(f.x), __float2bfloat16(f.y),
                              __float2bfloat16(f.z), __float2bfloat16(f.w)};
    ((uint64_t*)out)[i] = *(const uint64_t*)o;
}

// ---------------- transpose + cast: in fp32 [R][Cn] -> out bf16 [Cn][R] ----------------
__global__ __launch_bounds__(256) void transpose_cast(const float* __restrict__ in,
                                                      bf16* __restrict__ out, int R, int Cn) {
    __shared__ float tile[32][33];
    int bx = blockIdx.x * 32;
    int by = blockIdx.y * 32;
    int tx = threadIdx.x & 31, ty = threadIdx.x >> 5;
    for (int i = ty; i < 32; i += 8)
        tile[i][tx] = in[(size_t)(by + i) * Cn + bx + tx];
    __syncthreads();
    for (int i = ty; i < 32; i += 8)
        out[(size_t)(bx + i) * R + by + tx] = __float2bfloat16(tile[tx][i]);
}

// ---------------- transpose V per head: in [bh][2048][64] -> out [bh][64][2048] ----------------
__global__ __launch_bounds__(256) void transpose_v(const bf16* __restrict__ in,
                                                   bf16* __restrict__ out) {
    __shared__ bf16 tile[64][72];
    int bh = blockIdx.y;
    int t0 = blockIdx.x * 64;
    const bf16* ib = in + (size_t)bh * 2048 * 64 + (size_t)t0 * 64;
    bf16* ob = out + (size_t)bh * 64 * 2048 + t0;
    int r = threadIdx.x >> 2, c = (threadIdx.x & 3) * 16;
    *(ushort8*)&tile[r][c]     = *(const ushort8*)(ib + (size_t)r * 64 + c);
    *(ushort8*)&tile[r][c + 8] = *(const ushort8*)(ib + (size_t)r * 64 + c + 8);
    __syncthreads();
    int d = threadIdx.x >> 2, t = (threadIdx.x & 3) * 16;
    __align__(16) bf16 tmp[16];
    for (int j = 0; j < 16; ++j) tmp[j] = tile[t + j][d];
    *(ushort8*)(ob + (size_t)d * 2048 + t)     = *(const ushort8*)tmp;
    *(ushort8*)(ob + (size_t)d * 2048 + t + 8) = *(const ushort8*)(tmp + 8);
}

// ---------------- GEMM1: qkv = x @ w_qkv + b, scatter to q/k/v bf16 ----------------
// Q is pre-scaled by 0.125*log2(e) so flash can use exp2 without a per-score mul.
__global__ __launch_bounds__(256) void gemm_qkv(const bf16* __restrict__ A,
                                                const bf16* __restrict__ Bt,
                                                const float* __restrict__ bias,
                                                bf16* __restrict__ qb,
                                                bf16* __restrict__ kb,
                                                bf16* __restrict__ vb) {
    constexpr int K = 1024, T = 2048;
    constexpr float CS = 0.18033688f;  // 0.125 * log2(e)
    __shared__ __align__(16) bf16 Al[128 * 32];
    __shared__ __align__(16) bf16 Bl[128 * 32];
    int tid = threadIdx.x;
    int lane = tid & 63, w = tid >> 6;
    int wm = w >> 1, wn = w & 1;
    int l15 = lane & 15, quad = lane >> 4;
    int m0 = blockIdx.x * 128, n0 = blockIdx.y * 128;

    f32x4 acc[4][4] = {};
    for (int k0 = 0; k0 < K; k0 += 32) {
        __syncthreads();
        for (int it = 0; it < 2; ++it) {
            int e = (it * 256 + tid) * 8;
            int r = e >> 5, c = e & 31;
            gld_lds16(A  + (size_t)(m0 + r) * K + k0 + c, &Al[e]);
            gld_lds16(Bt + (size_t)(n0 + r) * K + k0 + c, &Bl[e]);
        }
        __syncthreads();
        bf16x8 af[4], bfr[4];
        for (int i = 0; i < 4; ++i)
            af[i] = *(const bf16x8*)&Al[(wm * 64 + i * 16 + l15) * 32 + quad * 8];
        for (int j = 0; j < 4; ++j)
            bfr[j] = *(const bf16x8*)&Bl[(wn * 64 + j * 16 + l15) * 32 + quad * 8];
        for (int i = 0; i < 4; ++i)
            for (int j = 0; j < 4; ++j)
                acc[i][j] = __builtin_amdgcn_mfma_f32_16x16x32_bf16(af[i], bfr[j], acc[i][j], 0, 0, 0);
    }
    for (int i = 0; i < 4; ++i) {
        int mbase = m0 + wm * 64 + i * 16 + quad * 4;
        for (int j = 0; j < 4; ++j) {
            int n = n0 + wn * 64 + j * 16 + l15;
            float bv = bias[n];
            for (int v = 0; v < 4; ++v) {
                int mm = mbase + v;
                int b = mm >> 11, t = mm & 2047;
                float val = acc[i][j][v] + bv;
                if (n < 1024) {
                    int h = n >> 6, d = n & 63;
                    qb[(((size_t)(b * 16 + h)) * T + t) * 64 + d] = __float2bfloat16(val * CS);
                } else if (n < 2048) {
                    int n2 = n - 1024; int h = n2 >> 6, d = n2 & 63;
                    kb[(((size_t)(b * 16 + h)) * T + t) * 64 + d] = __float2bfloat16(val);
                } else {
                    int n2 = n - 2048; int h = n2 >> 6, d = n2 & 63;
                    vb[(((size_t)(b * 16 + h)) * T + t) * 64 + d] = __float2bfloat16(val);
                }
            }
        }
    }
}

// ---------------- Flash attention (causal), S^T formulation, 256q x 64k tiles ----------
// Block: 256 q-rows (4 waves x 64 = 4 l15-sets), K-tile 64. Fixed-max softmax
// (Q pre-scaled by 0.125*log2e => p = exp2(s)). lsum computed by an extra
// ones-column MFMA (O1), so normalization needs no cross-lane shuffles.
// Grid flat 512; blocks c and c+256 land on the same CU and get complementary
// xq = (7-j, j) => every CU runs exactly 36 key-tiles.
__global__ __launch_bounds__(256, 2) void flash_attn(const bf16* __restrict__ qb,
                                                     const bf16* __restrict__ kbuf,
                                                     const bf16* __restrict__ vT,
                                                     bf16* __restrict__ ob) {
    constexpr int T = 2048;
    __shared__ __align__(16) bf16 Kl[64 * 64];          // [key][d], 8-elem d-blocks XOR-swizzled
    __shared__ __align__(16) bf16 Vl[64 * 64];          // [d][key], 8-elem key-blocks XOR-swizzled
    __shared__ __align__(16) bf16 Pl[16 * 16 * 72];     // [wave*4+set][qrow][key0..63], stride 72
    int tid = threadIdx.x;
    int lane = tid & 63, w = tid >> 6;
    int l15 = lane & 15, quad = lane >> 4;

    int g = blockIdx.x;
    int c8 = g >> 8;               // 0 or 1
    int j = (g >> 6) & 3;          // 0..3
    int bh = g & 63;
    int xq = c8 ? j : 7 - j;       // complementary pairing: (7-j) + j = 7
    int q0 = xq << 8;
    const bf16* qbase = qb   + (size_t)bh * T * 64;
    const bf16* kbase = kbuf + (size_t)bh * T * 64;
    const bf16* vbase = vT   + (size_t)bh * 64 * T;

    int qg[4];
    bf16x8 qa[4][2];
    for (int s = 0; s < 4; ++s) {
        qg[s] = q0 + w * 64 + s * 16 + l15;
        for (int c = 0; c < 2; ++c)
            qa[s][c] = *(const bf16x8*)(qbase + (size_t)qg[s] * 64 + c * 32 + quad * 8);
    }

    bf16x8 ones;
    for (int i = 0; i < 8; ++i) ones[i] = (__bf16)1.0f;

    f32x4 O[4][4] = {};
    f32x4 O1[4] = {};
    int h7 = l15 & 7;

    int nit = 4 * xq + 4;
    for (int t = 0; t < nit; ++t) {
        int kb = t << 6;
        __syncthreads();
        for (int it = 0; it < 2; ++it) {
            int off = (it * 256 + tid) * 8;
            int r = off >> 6, cb = (off >> 3) & 7;
            gld_lds16(kbase + (size_t)(kb + r) * 64 + ((cb ^ (r & 7)) << 3), &Kl[off]);
            gld_lds16(vbase + (size_t)r * T + kb + ((cb ^ (r & 7)) << 3), &Vl[off]);
        }
        __syncthreads();

        bool maskt = (t >= nit - 4);
        for (int jn = 0; jn < 4; ++jn) {
            int row = jn * 16 + l15;  // key row in Kl
            bf16x8 a0 = *(const bf16x8*)&Kl[row * 64 + ((quad ^ h7) << 3)];
            bf16x8 a1 = *(const bf16x8*)&Kl[row * 64 + (((4 + quad) ^ h7) << 3)];
            f32x4 sa[4] = {};
            for (int s = 0; s < 4; ++s) {
                sa[s] = __builtin_amdgcn_mfma_f32_16x16x32_bf16(a0, qa[s][0], sa[s], 0, 0, 0);
                sa[s] = __builtin_amdgcn_mfma_f32_16x16x32_bf16(a1, qa[s][1], sa[s], 0, 0, 0);
            }
            for (int s = 0; s < 4; ++s) {
                __align__(8) bf16 pb[4];
                for (int v = 0; v < 4; ++v) {
                    float p = exp2f(sa[s][v]);
                    if (maskt) {
                        int key = kb + jn * 16 + quad * 4 + v;
                        p = (key <= qg[s]) ? p : 0.f;
                    }
                    pb[v] = __float2bfloat16(p);
                }
                *(uint64_t*)&Pl[((w * 4 + s) * 16 + l15) * 72 + jn * 16 + quad * 4] =
                    *(const uint64_t*)pb;
            }
        }
        asm volatile("s_waitcnt lgkmcnt(0)" ::: "memory");
        bf16x8 pf[4][2];
        for (int s = 0; s < 4; ++s) {
            for (int c = 0; c < 2; ++c)
                pf[s][c] = *(const bf16x8*)&Pl[((w * 4 + s) * 16 + l15) * 72 + c * 32 + quad * 8];
            O1[s] = __builtin_amdgcn_mfma_f32_16x16x32_bf16(pf[s][0], ones, O1[s], 0, 0, 0);
            O1[s] = __builtin_amdgcn_mfma_f32_16x16x32_bf16(pf[s][1], ones, O1[s], 0, 0, 0);
        }
        for (int jd = 0; jd < 4; ++jd) {
            int vrow = jd * 16 + l15;  // d row in Vl
            bf16x8 v0 = *(const bf16x8*)&Vl[vrow * 64 + ((quad ^ h7) << 3)];
            bf16x8 v1 = *(const bf16x8*)&Vl[vrow * 64 + (((4 + quad) ^ h7) << 3)];
            for (int s = 0; s < 4; ++s) {
                O[s][jd] = __builtin_amdgcn_mfma_f32_16x16x32_bf16(pf[s][0], v0, O[s][jd], 0, 0, 0);
                O[s][jd] = __builtin_amdgcn_mfma_f32_16x16x32_bf16(pf[s][1], v1, O[s][jd], 0, 0, 0);
            }
        }
    }

    // O1[s][v] = sum_k P[qrow=quad*4+v][k]  (same lane as O[s][jd][v]) -> no shuffles
    int b = bh >> 4, h = bh & 15;
    for (int s = 0; s < 4; ++s) {
        float linv[4];
        for (int v = 0; v < 4; ++v) linv[v] = 1.f / O1[s][v];
        for (int jd = 0; jd < 4; ++jd) {
            for (int v = 0; v < 4; ++v) {
                int qr = q0 + w * 64 + s * 16 + quad * 4 + v;
                ob[((size_t)(b * T + qr)) * 1024 + h * 64 + jd * 16 + l15] =
                    __float2bfloat16(O[s][jd][v] * linv[v]);
            }
        }
    }
}

// ---------------- GEMM2: out = O @ w_proj + b_proj (fp32 out) ----------------
__global__ __launch_bounds__(256) void gemm_proj(const bf16* __restrict__ A,
                                                 const bf16* __restrict__ Bt,
                                                 const float* __restrict__ bias,
                                                 float* __restrict__ out) {
    constexpr int K = 1024, N = 1024;
    __shared__ __align__(16) bf16 Al[128 * 32];
    __shared__ __align__(16) bf16 Bl[128 * 32];
    int tid = threadIdx.x;
    int lane = tid & 63, w = tid >> 6;
    int wm = w >> 1, wn = w & 1;
    int l15 = lane & 15, quad = lane >> 4;
    int m0 = blockIdx.x * 128, n0 = blockIdx.y * 128;

    f32x4 acc[4][4] = {};
    for (int k0 = 0; k0 < K; k0 += 32) {
        __syncthreads();
        for (int it = 0; it < 2; ++it) {
            int e = (it * 256 + tid) * 8;
            int r = e >> 5, c = e & 31;
            gld_lds16(A  + (size_t)(m0 + r) * K + k0 + c, &Al[e]);
            gld_lds16(Bt + (size_t)(n0 + r) * K + k0 + c, &Bl[e]);
        }
        __syncthreads();
        bf16x8 af[4], bfr[4];
        for (int i = 0; i < 4; ++i)
            af[i] = *(const bf16x8*)&Al[(wm * 64 + i * 16 + l15) * 32 + quad * 8];
        for (int j = 0; j < 4; ++j)
            bfr[j] = *(const bf16x8*)&Bl[(wn * 64 + j * 16 + l15) * 32 + quad * 8];
        for (int i = 0; i < 4; ++i)
            for (int j = 0; j < 4; ++j)
                acc[i][j] = __builtin_amdgcn_mfma_f32_16x16x32_bf16(af[i], bfr[j], acc[i][j], 0, 0, 0);
    }
    for (int i = 0; i < 4; ++i) {
        int mbase = m0 + wm * 64 + i * 16 + quad * 4;
        for (int j = 0; j < 4; ++j) {
            int n = n0 + wn * 64 + j * 16 + l15;
            float bv = bias[n];
            for (int v = 0; v < 4; ++v)
                out[(size_t)(mbase + v) * N + n] = acc[i][j][v] + bv;
        }
    }
}

extern "C" void kernel_launch(void* const* d_in, const int* in_sizes, int n_in,
                              void* d_out, int out_size, void* d_ws, size_t ws_size,
                              hipStream_t stream) {
    (void)in_sizes; (void)n_in; (void)out_size; (void)ws_size;
    const float* x      = (const float*)d_in[0];
    const float* w_qkv  = (const float*)d_in[1];
    const float* b_qkv  = (const float*)d_in[2];
    const float* w_proj = (const float*)d_in[3];
    const float* b_proj = (const float*)d_in[4];
    float* out = (float*)d_out;

    char* ws = (char*)d_ws;
    bf16* xb     = (bf16*)(ws);                 // 16 MB [8192][1024]
    bf16* wqkvT  = (bf16*)(ws + (16u << 20));   //  6 MB [3072][1024]
    bf16* wprojT = (bf16*)(ws + (22u << 20));   //  2 MB [1024][1024]
    bf16* qbuf   = (bf16*)(ws + (24u << 20));   // 16 MB [B,H,T,D] (pre-scaled by CS)
    bf16* kbuf   = (bf16*)(ws + (40u << 20));   // 16 MB [B,H,T,D]
    bf16* vb     = (bf16*)(ws + (56u << 20));   // 16 MB [B,H,T,D] (dead after transpose_v)
    bf16* vTb    = (bf16*)(ws + (72u << 20));   // 16 MB [B,H,D,T]
    bf16* ob     = (bf16*)(ws + (56u << 20));   // aliases vb (safe: vb dead by then)

    cast_f32_bf16<<<8192, 256, 0, stream>>>(x, xb, 8192 * 1024 / 4);
    transpose_cast<<<dim3(3072 / 32, 1024 / 32), 256, 0, stream>>>(w_qkv, wqkvT, 1024, 3072);
    transpose_cast<<<dim3(1024 / 32, 1024 / 32), 256, 0, stream>>>(w_proj, wprojT, 1024, 1024);
    gemm_qkv<<<dim3(64, 24), 256, 0, stream>>>(xb, wqkvT, b_qkv, qbuf, kbuf, vb);
    transpose_v<<<dim3(32, 64), 256, 0, stream>>>(vb, vTb);
    flash_attn<<<512, 256, 0, stream>>>(qbuf, kbuf, vTb, ob);
    gemm_proj<<<dim3(64, 8), 256, 0, stream>>>(ob, wprojT, b_proj, out);
}

// Round 8
// 281.494 us; speedup vs baseline: 1.0969x; 1.0969x over previous
//
#include <hip/hip_runtime.h>
#include <hip/hip_bf16.h>
#include <math.h>

using bf16 = __hip_bfloat16;
typedef __bf16 bf16x8 __attribute__((ext_vector_type(8)));
typedef float  f32x4  __attribute__((ext_vector_type(4)));
typedef unsigned short ushort8 __attribute__((ext_vector_type(8)));

#define DEV __device__ __forceinline__

DEV void gld_lds16(const void* g, void* l) {
    __builtin_amdgcn_global_load_lds((const __attribute__((address_space(1))) void*)g,
                                     (__attribute__((address_space(3))) void*)l,
                                     16, 0, 0);
}

// ---------------- cast fp32 -> bf16 (flat) ----------------
__global__ __launch_bounds__(256) void cast_f32_bf16(const float* __restrict__ in,
                                                     bf16* __restrict__ out, int n4) {
    int i = blockIdx.x * blockDim.x + threadIdx.x;
    if (i >= n4) return;
    float4 f = ((const float4*)in)[i];
    __align__(8) bf16 o[4] = {__float2bfloat16(f.x), __float2bfloat16(f.y),
                              __float2bfloat16(f.z), __float2bfloat16(f.w)};
    ((uint64_t*)out)[i] = *(const uint64_t*)o;
}

// ---------------- transpose + cast: in fp32 [R][Cn] -> out bf16 [Cn][R] ----------------
__global__ __launch_bounds__(256) void transpose_cast(const float* __restrict__ in,
                                                      bf16* __restrict__ out, int R, int Cn) {
    __shared__ float tile[32][33];
    int bx = blockIdx.x * 32;
    int by = blockIdx.y * 32;
    int tx = threadIdx.x & 31, ty = threadIdx.x >> 5;
    for (int i = ty; i < 32; i += 8)
        tile[i][tx] = in[(size_t)(by + i) * Cn + bx + tx];
    __syncthreads();
    for (int i = ty; i < 32; i += 8)
        out[(size_t)(bx + i) * R + by + tx] = __float2bfloat16(tile[tx][i]);
}

// ---------------- transpose V per head: in [bh][2048][64] -> out [bh][64][2048] ----------------
__global__ __launch_bounds__(256) void transpose_v(const bf16* __restrict__ in,
                                                   bf16* __restrict__ out) {
    __shared__ bf16 tile[64][72];
    int bh = blockIdx.y;
    int t0 = blockIdx.x * 64;
    const bf16* ib = in + (size_t)bh * 2048 * 64 + (size_t)t0 * 64;
    bf16* ob = out + (size_t)bh * 64 * 2048 + t0;
    int r = threadIdx.x >> 2, c = (threadIdx.x & 3) * 16;
    *(ushort8*)&tile[r][c]     = *(const ushort8*)(ib + (size_t)r * 64 + c);
    *(ushort8*)&tile[r][c + 8] = *(const ushort8*)(ib + (size_t)r * 64 + c + 8);
    __syncthreads();
    int d = threadIdx.x >> 2, t = (threadIdx.x & 3) * 16;
    __align__(16) bf16 tmp[16];
    for (int j = 0; j < 16; ++j) tmp[j] = tile[t + j][d];
    *(ushort8*)(ob + (size_t)d * 2048 + t)     = *(const ushort8*)tmp;
    *(ushort8*)(ob + (size_t)d * 2048 + t + 8) = *(const ushort8*)(tmp + 8);
}

// ---------------- GEMM1: qkv = x @ w_qkv + b, scatter to q/k/v bf16 ----------------
// Q is pre-scaled by 0.125*log2(e) so flash can use exp2 without a per-score mul.
__global__ __launch_bounds__(256) void gemm_qkv(const bf16* __restrict__ A,
                                                const bf16* __restrict__ Bt,
                                                const float* __restrict__ bias,
                                                bf16* __restrict__ qb,
                                                bf16* __restrict__ kb,
                                                bf16* __restrict__ vb) {
    constexpr int K = 1024, T = 2048;
    constexpr float CS = 0.18033688f;  // 0.125 * log2(e)
    __shared__ __align__(16) bf16 Al[128 * 32];
    __shared__ __align__(16) bf16 Bl[128 * 32];
    int tid = threadIdx.x;
    int lane = tid & 63, w = tid >> 6;
    int wm = w >> 1, wn = w & 1;
    int l15 = lane & 15, quad = lane >> 4;
    int m0 = blockIdx.x * 128, n0 = blockIdx.y * 128;

    f32x4 acc[4][4] = {};
    for (int k0 = 0; k0 < K; k0 += 32) {
        __syncthreads();
        for (int it = 0; it < 2; ++it) {
            int e = (it * 256 + tid) * 8;
            int r = e >> 5, c = e & 31;
            gld_lds16(A  + (size_t)(m0 + r) * K + k0 + c, &Al[e]);
            gld_lds16(Bt + (size_t)(n0 + r) * K + k0 + c, &Bl[e]);
        }
        __syncthreads();
        bf16x8 af[4], bfr[4];
        for (int i = 0; i < 4; ++i)
            af[i] = *(const bf16x8*)&Al[(wm * 64 + i * 16 + l15) * 32 + quad * 8];
        for (int j = 0; j < 4; ++j)
            bfr[j] = *(const bf16x8*)&Bl[(wn * 64 + j * 16 + l15) * 32 + quad * 8];
        for (int i = 0; i < 4; ++i)
            for (int j = 0; j < 4; ++j)
                acc[i][j] = __builtin_amdgcn_mfma_f32_16x16x32_bf16(af[i], bfr[j], acc[i][j], 0, 0, 0);
    }
    for (int i = 0; i < 4; ++i) {
        int mbase = m0 + wm * 64 + i * 16 + quad * 4;
        for (int j = 0; j < 4; ++j) {
            int n = n0 + wn * 64 + j * 16 + l15;
            float bv = bias[n];
            for (int v = 0; v < 4; ++v) {
                int mm = mbase + v;
                int b = mm >> 11, t = mm & 2047;
                float val = acc[i][j][v] + bv;
                if (n < 1024) {
                    int h = n >> 6, d = n & 63;
                    qb[(((size_t)(b * 16 + h)) * T + t) * 64 + d] = __float2bfloat16(val * CS);
                } else if (n < 2048) {
                    int n2 = n - 1024; int h = n2 >> 6, d = n2 & 63;
                    kb[(((size_t)(b * 16 + h)) * T + t) * 64 + d] = __float2bfloat16(val);
                } else {
                    int n2 = n - 2048; int h = n2 >> 6, d = n2 & 63;
                    vb[(((size_t)(b * 16 + h)) * T + t) * 64 + d] = __float2bfloat16(val);
                }
            }
        }
    }
}

// ---------------- Flash attention (causal), S^T formulation, 128q x 64k tiles ----------
// Block: 128 q-rows (4 waves x 32 = 2 l15-sets), K-tile 64. Fixed-max softmax
// (Q pre-scaled by 0.125*log2e => p = exp2(s)). lsum via ones-column MFMA (O1):
// same lane mapping as O, so normalization needs no cross-lane shuffles.
// Grid is flat 1024; (xq, bh) decoded so the 4 co-resident blocks per CU have
// complementary causal weights (column sums = 30 => every CU runs 68 key-tiles).
__global__ __launch_bounds__(256, 4) void flash_attn(const bf16* __restrict__ qb,
                                                     const bf16* __restrict__ kbuf,
                                                     const bf16* __restrict__ vT,
                                                     bf16* __restrict__ ob) {
    constexpr int T = 2048;
    __shared__ __align__(16) bf16 Kl[64 * 64];          // [key][d], 8-elem d-blocks XOR-swizzled
    __shared__ __align__(16) bf16 Vl[64 * 64];          // [d][key], 8-elem key-blocks XOR-swizzled
    __shared__ __align__(16) bf16 Pl[4 * 2 * 16 * 72];  // [wave][set][qrow][key0..63], stride 72
    int tid = threadIdx.x;
    int lane = tid & 63, w = tid >> 6;
    int l15 = lane & 15, quad = lane >> 4;

    int g = blockIdx.x;
    int quarter = g >> 8;          // 0..3
    int j = (g >> 6) & 3;          // 0..3
    int bh = g & 63;
    int xq;
    switch (quarter) {             // column sums over quarters = 30 for every j
        case 0:  xq = 15 - j; break;
        case 1:  xq = 8 + j;  break;
        case 2:  xq = 4 + j;  break;
        default: xq = 3 - j;  break;
    }
    int q0 = xq << 7;
    const bf16* qbase = qb   + (size_t)bh * T * 64;
    const bf16* kbase = kbuf + (size_t)bh * T * 64;
    const bf16* vbase = vT   + (size_t)bh * 64 * T;

    int qg[2];
    bf16x8 qa[2][2];
    for (int s = 0; s < 2; ++s) {
        qg[s] = q0 + w * 32 + s * 16 + l15;
        for (int c = 0; c < 2; ++c)
            qa[s][c] = *(const bf16x8*)(qbase + (size_t)qg[s] * 64 + c * 32 + quad * 8);
    }

    bf16x8 ones;
    for (int i = 0; i < 8; ++i) ones[i] = (__bf16)1.0f;

    f32x4 O[2][4] = {};
    f32x4 O1[2] = {};
    int h7 = l15 & 7;

    int nit = 2 * xq + 2;
    for (int t = 0; t < nit; ++t) {
        int kb = t << 6;
        __syncthreads();
        for (int it = 0; it < 2; ++it) {
            int off = (it * 256 + tid) * 8;
            int r = off >> 6, cb = (off >> 3) & 7;
            gld_lds16(kbase + (size_t)(kb + r) * 64 + ((cb ^ (r & 7)) << 3), &Kl[off]);
            gld_lds16(vbase + (size_t)r * T + kb + ((cb ^ (r & 7)) << 3), &Vl[off]);
        }
        __syncthreads();

        bool maskt = (t >= nit - 2);
        for (int jn = 0; jn < 4; ++jn) {
            int row = jn * 16 + l15;  // key row in Kl
            bf16x8 a0 = *(const bf16x8*)&Kl[row * 64 + ((quad ^ h7) << 3)];
            bf16x8 a1 = *(const bf16x8*)&Kl[row * 64 + (((4 + quad) ^ h7) << 3)];
            f32x4 sa[2] = {};
            for (int s = 0; s < 2; ++s) {
                sa[s] = __builtin_amdgcn_mfma_f32_16x16x32_bf16(a0, qa[s][0], sa[s], 0, 0, 0);
                sa[s] = __builtin_amdgcn_mfma_f32_16x16x32_bf16(a1, qa[s][1], sa[s], 0, 0, 0);
            }
            for (int s = 0; s < 2; ++s) {
                __align__(8) bf16 pb[4];
                for (int v = 0; v < 4; ++v) {
                    float p = exp2f(sa[s][v]);
                    if (maskt) {
                        int key = kb + jn * 16 + quad * 4 + v;
                        p = (key <= qg[s]) ? p : 0.f;
                    }
                    pb[v] = __float2bfloat16(p);
                }
                *(uint64_t*)&Pl[((w * 2 + s) * 16 + l15) * 72 + jn * 16 + quad * 4] =
                    *(const uint64_t*)pb;
            }
        }
        asm volatile("s_waitcnt lgkmcnt(0)" ::: "memory");
        bf16x8 pf[2][2];
        for (int s = 0; s < 2; ++s) {
            for (int c = 0; c < 2; ++c)
                pf[s][c] = *(const bf16x8*)&Pl[((w * 2 + s) * 16 + l15) * 72 + c * 32 + quad * 8];
            O1[s] = __builtin_amdgcn_mfma_f32_16x16x32_bf16(pf[s][0], ones, O1[s], 0, 0, 0);
            O1[s] = __builtin_amdgcn_mfma_f32_16x16x32_bf16(pf[s][1], ones, O1[s], 0, 0, 0);
        }
        for (int jd = 0; jd < 4; ++jd) {
            int vrow = jd * 16 + l15;  // d row in Vl
            bf16x8 v0 = *(const bf16x8*)&Vl[vrow * 64 + ((quad ^ h7) << 3)];
            bf16x8 v1 = *(const bf16x8*)&Vl[vrow * 64 + (((4 + quad) ^ h7) << 3)];
            O[0][jd] = __builtin_amdgcn_mfma_f32_16x16x32_bf16(pf[0][0], v0, O[0][jd], 0, 0, 0);
            O[0][jd] = __builtin_amdgcn_mfma_f32_16x16x32_bf16(pf[0][1], v1, O[0][jd], 0, 0, 0);
            O[1][jd] = __builtin_amdgcn_mfma_f32_16x16x32_bf16(pf[1][0], v0, O[1][jd], 0, 0, 0);
            O[1][jd] = __builtin_amdgcn_mfma_f32_16x16x32_bf16(pf[1][1], v1, O[1][jd], 0, 0, 0);
        }
    }

    // O1[s][v] = sum_k P[qrow=quad*4+v][k]  (same lane as O[s][jd][v]) -> no shuffles
    int b = bh >> 4, h = bh & 15;
    for (int s = 0; s < 2; ++s) {
        float linv[4];
        for (int v = 0; v < 4; ++v) linv[v] = 1.f / O1[s][v];
        for (int jd = 0; jd < 4; ++jd) {
            for (int v = 0; v < 4; ++v) {
                int qr = q0 + w * 32 + s * 16 + quad * 4 + v;
                ob[((size_t)(b * T + qr)) * 1024 + h * 64 + jd * 16 + l15] =
                    __float2bfloat16(O[s][jd][v] * linv[v]);
            }
        }
    }
}

// ---------------- GEMM2: out = O @ w_proj + b_proj (fp32 out) ----------------
__global__ __launch_bounds__(256) void gemm_proj(const bf16* __restrict__ A,
                                                 const bf16* __restrict__ Bt,
                                                 const float* __restrict__ bias,
                                                 float* __restrict__ out) {
    constexpr int K = 1024, N = 1024;
    __shared__ __align__(16) bf16 Al[128 * 32];
    __shared__ __align__(16) bf16 Bl[128 * 32];
    int tid = threadIdx.x;
    int lane = tid & 63, w = tid >> 6;
    int wm = w >> 1, wn = w & 1;
    int l15 = lane & 15, quad = lane >> 4;
    int m0 = blockIdx.x * 128, n0 = blockIdx.y * 128;

    f32x4 acc[4][4] = {};
    for (int k0 = 0; k0 < K; k0 += 32) {
        __syncthreads();
        for (int it = 0; it < 2; ++it) {
            int e = (it * 256 + tid) * 8;
            int r = e >> 5, c = e & 31;
            gld_lds16(A  + (size_t)(m0 + r) * K + k0 + c, &Al[e]);
            gld_lds16(Bt + (size_t)(n0 + r) * K + k0 + c, &Bl[e]);
        }
        __syncthreads();
        bf16x8 af[4], bfr[4];
        for (int i = 0; i < 4; ++i)
            af[i] = *(const bf16x8*)&Al[(wm * 64 + i * 16 + l15) * 32 + quad * 8];
        for (int j = 0; j < 4; ++j)
            bfr[j] = *(const bf16x8*)&Bl[(wn * 64 + j * 16 + l15) * 32 + quad * 8];
        for (int i = 0; i < 4; ++i)
            for (int j = 0; j < 4; ++j)
                acc[i][j] = __builtin_amdgcn_mfma_f32_16x16x32_bf16(af[i], bfr[j], acc[i][j], 0, 0, 0);
    }
    for (int i = 0; i < 4; ++i) {
        int mbase = m0 + wm * 64 + i * 16 + quad * 4;
        for (int j = 0; j < 4; ++j) {
            int n = n0 + wn * 64 + j * 16 + l15;
            float bv = bias[n];
            for (int v = 0; v < 4; ++v)
                out[(size_t)(mbase + v) * N + n] = acc[i][j][v] + bv;
        }
    }
}

extern "C" void kernel_launch(void* const* d_in, const int* in_sizes, int n_in,
                              void* d_out, int out_size, void* d_ws, size_t ws_size,
                              hipStream_t stream) {
    (void)in_sizes; (void)n_in; (void)out_size; (void)ws_size;
    const float* x      = (const float*)d_in[0];
    const float* w_qkv  = (const float*)d_in[1];
    const float* b_qkv  = (const float*)d_in[2];
    const float* w_proj = (const float*)d_in[3];
    const float* b_proj = (const float*)d_in[4];
    float* out = (float*)d_out;

    char* ws = (char*)d_ws;
    bf16* xb     = (bf16*)(ws);                 // 16 MB [8192][1024]
    bf16* wqkvT  = (bf16*)(ws + (16u << 20));   //  6 MB [3072][1024]
    bf16* wprojT = (bf16*)(ws + (22u << 20));   //  2 MB [1024][1024]
    bf16* qbuf   = (bf16*)(ws + (24u << 20));   // 16 MB [B,H,T,D] (pre-scaled by CS)
    bf16* kbuf   = (bf16*)(ws + (40u << 20));   // 16 MB [B,H,T,D]
    bf16* vb     = (bf16*)(ws + (56u << 20));   // 16 MB [B,H,T,D] (dead after transpose_v)
    bf16* vTb    = (bf16*)(ws + (72u << 20));   // 16 MB [B,H,D,T]
    bf16* ob     = (bf16*)(ws + (56u << 20));   // aliases vb (safe: vb dead by then)

    cast_f32_bf16<<<8192, 256, 0, stream>>>(x, xb, 8192 * 1024 / 4);
    transpose_cast<<<dim3(3072 / 32, 1024 / 32), 256, 0, stream>>>(w_qkv, wqkvT, 1024, 3072);
    transpose_cast<<<dim3(1024 / 32, 1024 / 32), 256, 0, stream>>>(w_proj, wprojT, 1024, 1024);
    gemm_qkv<<<dim3(64, 24), 256, 0, stream>>>(xb, wqkvT, b_qkv, qbuf, kbuf, vb);
    transpose_v<<<dim3(32, 64), 256, 0, stream>>>(vb, vTb);
    flash_attn<<<1024, 256, 0, stream>>>(qbuf, kbuf, vTb, ob);
    gemm_proj<<<dim3(64, 8), 256, 0, stream>>>(ob, wprojT, b_proj, out);
}

// Round 9
// 261.562 us; speedup vs baseline: 1.1805x; 1.0762x over previous
//
#include <hip/hip_runtime.h>
#include <hip/hip_bf16.h>
#include <math.h>

using bf16 = __hip_bfloat16;
typedef __bf16 bf16x8 __attribute__((ext_vector_type(8)));
typedef float  f32x4  __attribute__((ext_vector_type(4)));
typedef unsigned short ushort8 __attribute__((ext_vector_type(8)));

#define DEV __device__ __forceinline__

DEV void gld_lds16(const void* g, void* l) {
    __builtin_amdgcn_global_load_lds((const __attribute__((address_space(1))) void*)g,
                                     (__attribute__((address_space(3))) void*)l,
                                     16, 0, 0);
}

// ---------------- cast fp32 -> bf16 (flat) ----------------
__global__ __launch_bounds__(256) void cast_f32_bf16(const float* __restrict__ in,
                                                     bf16* __restrict__ out, int n4) {
    int i = blockIdx.x * blockDim.x + threadIdx.x;
    if (i >= n4) return;
    float4 f = ((const float4*)in)[i];
    __align__(8) bf16 o[4] = {__float2bfloat16(f.x), __float2bfloat16(f.y),
                              __float2bfloat16(f.z), __float2bfloat16(f.w)};
    ((uint64_t*)out)[i] = *(const uint64_t*)o;
}

// ---------------- transpose + cast: in fp32 [R][Cn] -> out bf16 [Cn][R] ----------------
__global__ __launch_bounds__(256) void transpose_cast(const float* __restrict__ in,
                                                      bf16* __restrict__ out, int R, int Cn) {
    __shared__ float tile[32][33];
    int bx = blockIdx.x * 32;
    int by = blockIdx.y * 32;
    int tx = threadIdx.x & 31, ty = threadIdx.x >> 5;
    for (int i = ty; i < 32; i += 8)
        tile[i][tx] = in[(size_t)(by + i) * Cn + bx + tx];
    __syncthreads();
    for (int i = ty; i < 32; i += 8)
        out[(size_t)(bx + i) * R + by + tx] = __float2bfloat16(tile[tx][i]);
}

// ---------------- GEMM1: qkv = x @ w_qkv + b -> q (prescaled), k, vT ----------------
// Q is pre-scaled by 0.125*log2(e) so flash can use exp2 without a per-score mul.
// Each 128-col block lies wholly in q / k / v (boundaries are multiples of 128):
// mode decided once per block. Epilogue repacks via padded LDS tile and issues
// wide ushort8 stores; v-blocks store transposed directly into vT (no separate
// transpose kernel, no vb round-trip).
__global__ __launch_bounds__(256) void gemm_qkv(const bf16* __restrict__ A,
                                                const bf16* __restrict__ Bt,
                                                const float* __restrict__ bias,
                                                bf16* __restrict__ qb,
                                                bf16* __restrict__ kb,
                                                bf16* __restrict__ vTb) {
    constexpr int K = 1024, T = 2048;
    constexpr float CS = 0.18033688f;  // 0.125 * log2(e)
    __shared__ __align__(16) bf16 Al[128 * 32];
    __shared__ __align__(16) bf16 Bl[128 * 32];
    __shared__ __align__(16) bf16 Et[32 * 136];  // epilogue staging, pad->272B rows
    int tid = threadIdx.x;
    int lane = tid & 63, w = tid >> 6;
    int wm = w >> 1, wn = w & 1;
    int l15 = lane & 15, quad = lane >> 4;
    int m0 = blockIdx.x * 128, n0 = blockIdx.y * 128;

    f32x4 acc[4][4] = {};
    for (int k0 = 0; k0 < K; k0 += 32) {
        __syncthreads();
        for (int it = 0; it < 2; ++it) {
            int e = (it * 256 + tid) * 8;
            int r = e >> 5, c = e & 31;
            gld_lds16(A  + (size_t)(m0 + r) * K + k0 + c, &Al[e]);
            gld_lds16(Bt + (size_t)(n0 + r) * K + k0 + c, &Bl[e]);
        }
        __syncthreads();
        bf16x8 af[4], bfr[4];
        for (int i = 0; i < 4; ++i)
            af[i] = *(const bf16x8*)&Al[(wm * 64 + i * 16 + l15) * 32 + quad * 8];
        for (int j = 0; j < 4; ++j)
            bfr[j] = *(const bf16x8*)&Bl[(wn * 64 + j * 16 + l15) * 32 + quad * 8];
        for (int i = 0; i < 4; ++i)
            for (int j = 0; j < 4; ++j)
                acc[i][j] = __builtin_amdgcn_mfma_f32_16x16x32_bf16(af[i], bfr[j], acc[i][j], 0, 0, 0);
    }

    int mode = (blockIdx.y < 8) ? 0 : (blockIdx.y < 16 ? 1 : 2);  // q / k / v
    float bv[4];
    for (int j = 0; j < 4; ++j)
        bv[j] = bias[n0 + wn * 64 + j * 16 + l15];
    float scl = (mode == 0) ? CS : 1.0f;

    for (int i = 0; i < 4; ++i) {
        __syncthreads();
        for (int j = 0; j < 4; ++j)
            for (int v = 0; v < 4; ++v)
                Et[(wm * 16 + quad * 4 + v) * 136 + wn * 64 + j * 16 + l15] =
                    __float2bfloat16((acc[i][j][v] + bv[j]) * scl);
        __syncthreads();
        if (mode < 2) {
            // row readout: 16 consecutive n at one row -> 2x ushort8 stores
            int r = tid >> 3, cc = (tid & 7) * 16;
            int m = m0 + i * 16 + (r < 16 ? r : r + 48);
            int b = m >> 11, t = m & 2047;
            int n = (n0 & 1023) + cc;
            int h = n >> 6, d = n & 63;
            bf16* dst = (mode == 0 ? qb : kb) + (((size_t)(b * 16 + h)) * T + t) * 64 + d;
            ushort8 u0 = *(const ushort8*)&Et[r * 136 + cc];
            ushort8 u1 = *(const ushort8*)&Et[r * 136 + cc + 8];
            *(ushort8*)dst = u0;
            *(ushort8*)(dst + 8) = u1;
        } else {
            // transposed readout: 16 consecutive t at one d -> 2x ushort8 into vT
            int run = tid >> 7, d = tid & 127;
            int t0 = m0 + i * 16 + run * 64;
            int b = t0 >> 11, tt = t0 & 2047;
            int n = (n0 & 1023) + d;
            int h = n >> 6, dd = n & 63;
            __align__(16) bf16 tmp[16];
            for (int jj = 0; jj < 16; ++jj)
                tmp[jj] = Et[(run * 16 + jj) * 136 + d];
            bf16* dst = vTb + (((size_t)(b * 16 + h)) * 64 + dd) * T + tt;
            *(ushort8*)dst = *(const ushort8*)tmp;
            *(ushort8*)(dst + 8) = *(const ushort8*)(tmp + 8);
        }
    }
}

// ---------------- Flash attention (causal), S^T formulation, 128q x 64k tiles ----------
// Block: 128 q-rows (4 waves x 32 = 2 l15-sets), K-tile 64. Fixed-max softmax
// (Q pre-scaled by 0.125*log2e => p = exp2(s)). lsum via ones-column MFMA (O1):
// same lane mapping as O, so normalization needs no cross-lane shuffles.
// Grid is flat 1024; (xq, bh) decoded so the 4 co-resident blocks per CU have
// complementary causal weights (column sums = 30 => every CU runs 68 key-tiles).
__global__ __launch_bounds__(256, 4) void flash_attn(const bf16* __restrict__ qb,
                                                     const bf16* __restrict__ kbuf,
                                                     const bf16* __restrict__ vT,
                                                     bf16* __restrict__ ob) {
    constexpr int T = 2048;
    __shared__ __align__(16) bf16 Kl[64 * 64];          // [key][d], 8-elem d-blocks XOR-swizzled
    __shared__ __align__(16) bf16 Vl[64 * 64];          // [d][key], 8-elem key-blocks XOR-swizzled
    __shared__ __align__(16) bf16 Pl[4 * 2 * 16 * 72];  // [wave][set][qrow][key0..63], stride 72
    int tid = threadIdx.x;
    int lane = tid & 63, w = tid >> 6;
    int l15 = lane & 15, quad = lane >> 4;

    int g = blockIdx.x;
    int quarter = g >> 8;          // 0..3
    int j = (g >> 6) & 3;          // 0..3
    int bh = g & 63;
    int xq;
    switch (quarter) {             // column sums over quarters = 30 for every j
        case 0:  xq = 15 - j; break;
        case 1:  xq = 8 + j;  break;
        case 2:  xq = 4 + j;  break;
        default: xq = 3 - j;  break;
    }
    int q0 = xq << 7;
    const bf16* qbase = qb   + (size_t)bh * T * 64;
    const bf16* kbase = kbuf + (size_t)bh * T * 64;
    const bf16* vbase = vT   + (size_t)bh * 64 * T;

    int qg[2];
    bf16x8 qa[2][2];
    for (int s = 0; s < 2; ++s) {
        qg[s] = q0 + w * 32 + s * 16 + l15;
        for (int c = 0; c < 2; ++c)
            qa[s][c] = *(const bf16x8*)(qbase + (size_t)qg[s] * 64 + c * 32 + quad * 8);
    }

    bf16x8 ones;
    for (int i = 0; i < 8; ++i) ones[i] = (__bf16)1.0f;

    f32x4 O[2][4] = {};
    f32x4 O1[2] = {};
    int h7 = l15 & 7;

    int nit = 2 * xq + 2;
    for (int t = 0; t < nit; ++t) {
        int kb = t << 6;
        __syncthreads();
        for (int it = 0; it < 2; ++it) {
            int off = (it * 256 + tid) * 8;
            int r = off >> 6, cb = (off >> 3) & 7;
            gld_lds16(kbase + (size_t)(kb + r) * 64 + ((cb ^ (r & 7)) << 3), &Kl[off]);
            gld_lds16(vbase + (size_t)r * T + kb + ((cb ^ (r & 7)) << 3), &Vl[off]);
        }
        __syncthreads();

        bool maskt = (t >= nit - 2);
        for (int jn = 0; jn < 4; ++jn) {
            int row = jn * 16 + l15;  // key row in Kl
            bf16x8 a0 = *(const bf16x8*)&Kl[row * 64 + ((quad ^ h7) << 3)];
            bf16x8 a1 = *(const bf16x8*)&Kl[row * 64 + (((4 + quad) ^ h7) << 3)];
            f32x4 sa[2] = {};
            for (int s = 0; s < 2; ++s) {
                sa[s] = __builtin_amdgcn_mfma_f32_16x16x32_bf16(a0, qa[s][0], sa[s], 0, 0, 0);
                sa[s] = __builtin_amdgcn_mfma_f32_16x16x32_bf16(a1, qa[s][1], sa[s], 0, 0, 0);
            }
            for (int s = 0; s < 2; ++s) {
                __align__(8) bf16 pb[4];
                for (int v = 0; v < 4; ++v) {
                    float p = exp2f(sa[s][v]);
                    if (maskt) {
                        int key = kb + jn * 16 + quad * 4 + v;
                        p = (key <= qg[s]) ? p : 0.f;
                    }
                    pb[v] = __float2bfloat16(p);
                }
                *(uint64_t*)&Pl[((w * 2 + s) * 16 + l15) * 72 + jn * 16 + quad * 4] =
                    *(const uint64_t*)pb;
            }
        }
        asm volatile("s_waitcnt lgkmcnt(0)" ::: "memory");
        bf16x8 pf[2][2];
        for (int s = 0; s < 2; ++s) {
            for (int c = 0; c < 2; ++c)
                pf[s][c] = *(const bf16x8*)&Pl[((w * 2 + s) * 16 + l15) * 72 + c * 32 + quad * 8];
            O1[s] = __builtin_amdgcn_mfma_f32_16x16x32_bf16(pf[s][0], ones, O1[s], 0, 0, 0);
            O1[s] = __builtin_amdgcn_mfma_f32_16x16x32_bf16(pf[s][1], ones, O1[s], 0, 0, 0);
        }
        for (int jd = 0; jd < 4; ++jd) {
            int vrow = jd * 16 + l15;  // d row in Vl
            bf16x8 v0 = *(const bf16x8*)&Vl[vrow * 64 + ((quad ^ h7) << 3)];
            bf16x8 v1 = *(const bf16x8*)&Vl[vrow * 64 + (((4 + quad) ^ h7) << 3)];
            O[0][jd] = __builtin_amdgcn_mfma_f32_16x16x32_bf16(pf[0][0], v0, O[0][jd], 0, 0, 0);
            O[0][jd] = __builtin_amdgcn_mfma_f32_16x16x32_bf16(pf[0][1], v1, O[0][jd], 0, 0, 0);
            O[1][jd] = __builtin_amdgcn_mfma_f32_16x16x32_bf16(pf[1][0], v0, O[1][jd], 0, 0, 0);
            O[1][jd] = __builtin_amdgcn_mfma_f32_16x16x32_bf16(pf[1][1], v1, O[1][jd], 0, 0, 0);
        }
    }

    // O1[s][v] = sum_k P[qrow=quad*4+v][k]  (same lane as O[s][jd][v]) -> no shuffles
    int b = bh >> 4, h = bh & 15;
    for (int s = 0; s < 2; ++s) {
        float linv[4];
        for (int v = 0; v < 4; ++v) linv[v] = 1.f / O1[s][v];
        for (int jd = 0; jd < 4; ++jd) {
            for (int v = 0; v < 4; ++v) {
                int qr = q0 + w * 32 + s * 16 + quad * 4 + v;
                ob[((size_t)(b * T + qr)) * 1024 + h * 64 + jd * 16 + l15] =
                    __float2bfloat16(O[s][jd][v] * linv[v]);
            }
        }
    }
}

// ---------------- GEMM2: out = O @ w_proj + b_proj (fp32 out) ----------------
__global__ __launch_bounds__(256) void gemm_proj(const bf16* __restrict__ A,
                                                 const bf16* __restrict__ Bt,
                                                 const float* __restrict__ bias,
                                                 float* __restrict__ out) {
    constexpr int K = 1024, N = 1024;
    __shared__ __align__(16) bf16 Al[128 * 32];
    __shared__ __align__(16) bf16 Bl[128 * 32];
    int tid = threadIdx.x;
    int lane = tid & 63, w = tid >> 6;
    int wm = w >> 1, wn = w & 1;
    int l15 = lane & 15, quad = lane >> 4;
    int m0 = blockIdx.x * 128, n0 = blockIdx.y * 128;

    f32x4 acc[4][4] = {};
    for (int k0 = 0; k0 < K; k0 += 32) {
        __syncthreads();
        for (int it = 0; it < 2; ++it) {
            int e = (it * 256 + tid) * 8;
            int r = e >> 5, c = e & 31;
            gld_lds16(A  + (size_t)(m0 + r) * K + k0 + c, &Al[e]);
            gld_lds16(Bt + (size_t)(n0 + r) * K + k0 + c, &Bl[e]);
        }
        __syncthreads();
        bf16x8 af[4], bfr[4];
        for (int i = 0; i < 4; ++i)
            af[i] = *(const bf16x8*)&Al[(wm * 64 + i * 16 + l15) * 32 + quad * 8];
        for (int j = 0; j < 4; ++j)
            bfr[j] = *(const bf16x8*)&Bl[(wn * 64 + j * 16 + l15) * 32 + quad * 8];
        for (int i = 0; i < 4; ++i)
            for (int j = 0; j < 4; ++j)
                acc[i][j] = __builtin_amdgcn_mfma_f32_16x16x32_bf16(af[i], bfr[j], acc[i][j], 0, 0, 0);
    }
    for (int i = 0; i < 4; ++i) {
        int mbase = m0 + wm * 64 + i * 16 + quad * 4;
        for (int j = 0; j < 4; ++j) {
            int n = n0 + wn * 64 + j * 16 + l15;
            float bv = bias[n];
            for (int v = 0; v < 4; ++v)
                out[(size_t)(mbase + v) * N + n] = acc[i][j][v] + bv;
        }
    }
}

extern "C" void kernel_launch(void* const* d_in, const int* in_sizes, int n_in,
                              void* d_out, int out_size, void* d_ws, size_t ws_size,
                              hipStream_t stream) {
    (void)in_sizes; (void)n_in; (void)out_size; (void)ws_size;
    const float* x      = (const float*)d_in[0];
    const float* w_qkv  = (const float*)d_in[1];
    const float* b_qkv  = (const float*)d_in[2];
    const float* w_proj = (const float*)d_in[3];
    const float* b_proj = (const float*)d_in[4];
    float* out = (float*)d_out;

    char* ws = (char*)d_ws;
    bf16* xb     = (bf16*)(ws);                 // 16 MB [8192][1024]
    bf16* wqkvT  = (bf16*)(ws + (16u << 20));   //  6 MB [3072][1024]
    bf16* wprojT = (bf16*)(ws + (22u << 20));   //  2 MB [1024][1024]
    bf16* qbuf   = (bf16*)(ws + (24u << 20));   // 16 MB [B,H,T,D] (pre-scaled by CS)
    bf16* kbuf   = (bf16*)(ws + (40u << 20));   // 16 MB [B,H,T,D]
    bf16* vTb    = (bf16*)(ws + (72u << 20));   // 16 MB [B,H,D,T] (written by gemm_qkv)
    bf16* ob     = (bf16*)(ws + (56u << 20));   // 16 MB [8192][1024]

    cast_f32_bf16<<<8192, 256, 0, stream>>>(x, xb, 8192 * 1024 / 4);
    transpose_cast<<<dim3(3072 / 32, 1024 / 32), 256, 0, stream>>>(w_qkv, wqkvT, 1024, 3072);
    transpose_cast<<<dim3(1024 / 32, 1024 / 32), 256, 0, stream>>>(w_proj, wprojT, 1024, 1024);
    gemm_qkv<<<dim3(64, 24), 256, 0, stream>>>(xb, wqkvT, b_qkv, qbuf, kbuf, vTb);
    flash_attn<<<1024, 256, 0, stream>>>(qbuf, kbuf, vTb, ob);
    gemm_proj<<<dim3(64, 8), 256, 0, stream>>>(ob, wprojT, b_proj, out);
}